// Round 1
// 1805.210 us; speedup vs baseline: 1.7190x; 1.7190x over previous
//
#include <hip/hip_runtime.h>
#include <math.h>

#define N_NODES 100000
#define N_EDGES 1600000
#define DIM     128
#define NLAYER  5
#define NGRAPH  128
#define NTASK   10
#define NBOND   4
#define BN_EPS  1e-5f

// ---------------------------------------------------------------- histograms
__global__ __launch_bounds__(256) void hist_kernel(
    const int* __restrict__ row, const int* __restrict__ col,
    int* __restrict__ cnt_row, int* __restrict__ cnt_col) {
  int i = blockIdx.x * blockDim.x + threadIdx.x;
  int stride = gridDim.x * blockDim.x;
  for (; i < N_EDGES; i += stride) {
    atomicAdd(&cnt_row[row[i]], 1);
    atomicAdd(&cnt_col[col[i]], 1);
  }
}

__global__ __launch_bounds__(256) void deg_kernel(
    const int* __restrict__ cnt_row, float* __restrict__ deg, float* __restrict__ dinv) {
  int i = blockIdx.x * blockDim.x + threadIdx.x;
  if (i < N_NODES) {
    float d = (float)cnt_row[i] + 1.0f;
    deg[i] = d;
    dinv[i] = rsqrtf(d);
  }
}

// ---------------------------------------------------------------- scan (CSR offsets)
__global__ __launch_bounds__(256) void scan1_kernel(
    const int* __restrict__ cnt, int* __restrict__ excl, int* __restrict__ bsum) {
  __shared__ int s[256];
  int t = threadIdx.x;
  int i = blockIdx.x * 256 + t;
  int v = (i < N_NODES) ? cnt[i] : 0;
  s[t] = v;
  __syncthreads();
  for (int off = 1; off < 256; off <<= 1) {
    int add = (t >= off) ? s[t - off] : 0;
    __syncthreads();
    s[t] += add;
    __syncthreads();
  }
  if (i < N_NODES) excl[i] = s[t] - v;   // exclusive within block
  if (t == 255) bsum[blockIdx.x] = s[255];
}

__global__ __launch_bounds__(512) void scan2_kernel(
    const int* __restrict__ bsum, int* __restrict__ bexcl, int nb) {
  __shared__ int s[512];
  int t = threadIdx.x;
  int v = (t < nb) ? bsum[t] : 0;
  s[t] = v;
  __syncthreads();
  for (int off = 1; off < 512; off <<= 1) {
    int add = (t >= off) ? s[t - off] : 0;
    __syncthreads();
    s[t] += add;
    __syncthreads();
  }
  if (t < nb) bexcl[t] = s[t] - v;
}

__global__ __launch_bounds__(256) void scan3_kernel(
    int* __restrict__ excl, const int* __restrict__ bexcl) {
  int i = blockIdx.x * 256 + threadIdx.x;
  if (i < N_NODES) excl[i] += bexcl[blockIdx.x];
  if (i == 0) excl[N_NODES] = N_EDGES;
}

// ---------------------------------------------------------------- CSR scatter
__global__ __launch_bounds__(256) void scatter_kernel(
    const int* __restrict__ row, const int* __restrict__ col,
    const int* __restrict__ attr, const int* __restrict__ csr_off,
    int* __restrict__ pos, const float* __restrict__ dinv,
    int* __restrict__ src_pack, float* __restrict__ enorm) {
  int e = blockIdx.x * blockDim.x + threadIdx.x;
  int stride = gridDim.x * blockDim.x;
  for (; e < N_EDGES; e += stride) {
    int d = col[e];
    int s = row[e];
    int p = csr_off[d] + atomicAdd(&pos[d], 1);
    src_pack[p] = s | (attr[e] << 20);         // src < 2^20, attr < 4
    enorm[p] = dinv[s] * dinv[d];
  }
}

// ---------------------------------------------------------------- GEMM: hx = act(hin) @ W + b
// Thread j owns output column j; W[:,j] lives in 128 VGPRs (fully unrolled).
// h rows staged in LDS, read as broadcast float4 -> 4 FMA per ds_read_b128.
// useact: apply previous layer's BN scale/shift + relu while staging input.
#define GROWS 8
__global__ __launch_bounds__(128) void gemm_kernel(
    const float* __restrict__ hin, const float* __restrict__ W,
    const float* __restrict__ bias, const float* __restrict__ scale,
    const float* __restrict__ shift, int useact,
    float* __restrict__ hx, float* __restrict__ bnzero) {
  __shared__ float hs[GROWS][DIM];
  __shared__ float sscale[DIM], sshift[DIM];
  int t = threadIdx.x;  // 0..127
  if (blockIdx.x == 0) {       // zero BN accumulators for this layer (agg runs after)
    bnzero[t] = 0.0f;
    bnzero[t + 128] = 0.0f;
  }
  if (useact) { sscale[t] = scale[t]; sshift[t] = shift[t]; }
  float wreg[DIM];
#pragma unroll
  for (int k = 0; k < DIM; k++) wreg[k] = W[(size_t)k * DIM + t];
  float breg = bias[t];

  const int ntiles = N_NODES / GROWS;  // 100000 % 8 == 0
  for (int tile = blockIdx.x; tile < ntiles; tile += gridDim.x) {
    int r0 = tile * GROWS;
    __syncthreads();  // protect hs from previous iteration's readers
    {
      const float4* src = (const float4*)(hin + (size_t)r0 * DIM);
      float4* dst = (float4*)(&hs[0][0]);
#pragma unroll
      for (int it = 0; it < 2; it++) {
        int q = t + it * 128;             // 256 float4 total
        float4 v = src[q];
        if (useact) {
          int k = (q * 4) & (DIM - 1);
          v.x = fmaxf(fmaf(v.x, sscale[k],     sshift[k]),     0.f);
          v.y = fmaxf(fmaf(v.y, sscale[k + 1], sshift[k + 1]), 0.f);
          v.z = fmaxf(fmaf(v.z, sscale[k + 2], sshift[k + 2]), 0.f);
          v.w = fmaxf(fmaf(v.w, sscale[k + 3], sshift[k + 3]), 0.f);
        }
        dst[q] = v;
      }
    }
    __syncthreads();
    float acc[GROWS];
#pragma unroll
    for (int r = 0; r < GROWS; r++) acc[r] = breg;
#pragma unroll
    for (int k4 = 0; k4 < DIM / 4; k4++) {
#pragma unroll
      for (int r = 0; r < GROWS; r++) {
        float4 h4 = ((const float4*)(&hs[r][0]))[k4];  // broadcast read
        acc[r] = fmaf(h4.x, wreg[4 * k4],     acc[r]);
        acc[r] = fmaf(h4.y, wreg[4 * k4 + 1], acc[r]);
        acc[r] = fmaf(h4.z, wreg[4 * k4 + 2], acc[r]);
        acc[r] = fmaf(h4.w, wreg[4 * k4 + 3], acc[r]);
      }
    }
#pragma unroll
    for (int r = 0; r < GROWS; r++)
      hx[(size_t)(r0 + r) * DIM + t] = acc[r];
  }
}

// ---------------------------------------------------------------- edge aggregation
// One wave per destination node; lane&31 owns features [4q..4q+3] via float4.
// The two 32-lane halves of the wave process two edges concurrently, and the
// edge loop is manually unrolled 2x -> 4 independent 512B row gathers in
// flight per wave (latency-bound fix). Halves combined via shfl_xor(32).
// BN sum/sumsq: registers -> LDS block reduce -> one global atomic per feature.
__global__ __launch_bounds__(256) void agg_kernel(
    const float* __restrict__ hx, const int* __restrict__ csr_off,
    const int* __restrict__ src_pack, const float* __restrict__ enorm,
    const float* __restrict__ bond, const float* __restrict__ root,
    const float* __restrict__ deg, float* __restrict__ h2,
    float* __restrict__ bnbuf) {
  __shared__ float4 bondS[NBOND * 32];
  __shared__ float4 rootS[32];
  __shared__ float sbn[256];
  int t = threadIdx.x;
  if (t < NBOND * 32) bondS[t] = ((const float4*)bond)[t];
  if (t < 32) rootS[t] = ((const float4*)root)[t];
  sbn[t] = 0.0f;
  __syncthreads();

  int lane = t & 63;
  int laneq = lane & 31;   // feature quad owner
  int half = lane >> 5;    // which edge of the pair
  int wid = t >> 6;
  int gw = blockIdx.x * 4 + wid;
  int nw = gridDim.x * 4;
  const float4* hx4 = (const float4*)hx;
  float4* h24 = (float4*)h2;

  float s0 = 0.f, s1 = 0.f, s2 = 0.f, s3 = 0.f;
  float q0 = 0.f, q1 = 0.f, q2 = 0.f, q3 = 0.f;
  for (int n = gw; n < N_NODES; n += nw) {
    int e0 = csr_off[n], e1 = csr_off[n + 1];
    float a0 = 0.f, a1 = 0.f, a2 = 0.f, a3 = 0.f;
    int e = e0 + half;
    // unrolled 2x: edges e and e+2 for this half-wave
    for (; e + 2 < e1; e += 4) {
      int sp0 = src_pack[e];
      int sp1 = src_pack[e + 2];
      float nr0 = enorm[e];
      float nr1 = enorm[e + 2];
      float4 v0 = hx4[(size_t)(sp0 & 0xFFFFF) * 32 + laneq];
      float4 v1 = hx4[(size_t)(sp1 & 0xFFFFF) * 32 + laneq];
      float4 b0 = bondS[(sp0 >> 20) * 32 + laneq];
      float4 b1 = bondS[(sp1 >> 20) * 32 + laneq];
      a0 = fmaf(nr0, fmaxf(v0.x + b0.x, 0.f), a0);
      a1 = fmaf(nr0, fmaxf(v0.y + b0.y, 0.f), a1);
      a2 = fmaf(nr0, fmaxf(v0.z + b0.z, 0.f), a2);
      a3 = fmaf(nr0, fmaxf(v0.w + b0.w, 0.f), a3);
      a0 = fmaf(nr1, fmaxf(v1.x + b1.x, 0.f), a0);
      a1 = fmaf(nr1, fmaxf(v1.y + b1.y, 0.f), a1);
      a2 = fmaf(nr1, fmaxf(v1.z + b1.z, 0.f), a2);
      a3 = fmaf(nr1, fmaxf(v1.w + b1.w, 0.f), a3);
    }
    for (; e < e1; e += 2) {
      int sp = src_pack[e];
      float nrm = enorm[e];
      float4 v = hx4[(size_t)(sp & 0xFFFFF) * 32 + laneq];
      float4 eb = bondS[(sp >> 20) * 32 + laneq];
      a0 = fmaf(nrm, fmaxf(v.x + eb.x, 0.f), a0);
      a1 = fmaf(nrm, fmaxf(v.y + eb.y, 0.f), a1);
      a2 = fmaf(nrm, fmaxf(v.z + eb.z, 0.f), a2);
      a3 = fmaf(nrm, fmaxf(v.w + eb.w, 0.f), a3);
    }
    // combine the two halves (lane l and l^32 hold partials for same features)
    a0 += __shfl_xor(a0, 32, 64);
    a1 += __shfl_xor(a1, 32, 64);
    a2 += __shfl_xor(a2, 32, 64);
    a3 += __shfl_xor(a3, 32, 64);
    if (half == 0) {
      float inv = 1.0f / deg[n];
      float4 v = hx4[(size_t)n * 32 + laneq];
      float4 r = rootS[laneq];
      a0 += fmaxf(v.x + r.x, 0.f) * inv;
      a1 += fmaxf(v.y + r.y, 0.f) * inv;
      a2 += fmaxf(v.z + r.z, 0.f) * inv;
      a3 += fmaxf(v.w + r.w, 0.f) * inv;
      float4 o;
      o.x = a0; o.y = a1; o.z = a2; o.w = a3;
      h24[(size_t)n * 32 + laneq] = o;
      s0 += a0; s1 += a1; s2 += a2; s3 += a3;
      q0 += a0 * a0; q1 += a1 * a1; q2 += a2 * a2; q3 += a3 * a3;
    }
  }
  // block-level BN reduction: LDS atomics, then one global atomic per feature
  if (half == 0) {
    int f = 4 * laneq;
    atomicAdd(&sbn[f + 0], s0);
    atomicAdd(&sbn[f + 1], s1);
    atomicAdd(&sbn[f + 2], s2);
    atomicAdd(&sbn[f + 3], s3);
    atomicAdd(&sbn[128 + f + 0], q0);
    atomicAdd(&sbn[128 + f + 1], q1);
    atomicAdd(&sbn[128 + f + 2], q2);
    atomicAdd(&sbn[128 + f + 3], q3);
  }
  __syncthreads();
  atomicAdd(&bnbuf[t], sbn[t]);
}

// ---------------------------------------------------------------- BN finalize
__global__ __launch_bounds__(128) void bnfin_kernel(
    const float* __restrict__ bnbuf, const float* __restrict__ gamma,
    const float* __restrict__ beta, float* __restrict__ scale,
    float* __restrict__ shift) {
  int d = threadIdx.x;
  const float invN = 1.0f / (float)N_NODES;
  float mu = bnbuf[d] * invN;
  float ex2 = bnbuf[128 + d] * invN;
  float var = ex2 - mu * mu;
  float inv = rsqrtf(var + BN_EPS);
  float sc = gamma[d] * inv;
  scale[d] = sc;
  shift[d] = fmaf(-mu, sc, beta[d]);
}

// ---------------------------------------------------------------- pooling (batch is sorted)
__global__ __launch_bounds__(256) void pool_kernel(
    const float* __restrict__ h2, const int* __restrict__ batch,
    const float* __restrict__ scale, const float* __restrict__ shift,
    float* __restrict__ pool, float* __restrict__ pcnt) {
  int t = threadIdx.x;
  int lane = t & 63;
  int wid = t >> 6;
  int gw = blockIdx.x * 4 + wid;
  int nw = gridDim.x * 4;
  int chunk = (N_NODES + nw - 1) / nw;
  int n0 = gw * chunk;
  int n1 = min(n0 + chunk, N_NODES);
  if (n0 >= N_NODES) return;
  const float2* h22 = (const float2*)h2;
  int f0 = 2 * lane, f1 = f0 + 1;
  float sc0 = scale[f0], sc1 = scale[f1], sh0 = shift[f0], sh1 = shift[f1];
  int curg = batch[n0];
  float a0 = 0.f, a1 = 0.f, c = 0.f;
  for (int n = n0; n < n1; n++) {
    int g = batch[n];
    if (g != curg) {
      atomicAdd(&pool[curg * DIM + f0], a0);
      atomicAdd(&pool[curg * DIM + f1], a1);
      if (lane == 0) atomicAdd(&pcnt[curg], c);
      a0 = a1 = c = 0.f;
      curg = g;
    }
    float2 v = h22[(size_t)n * 64 + lane];
    a0 += fmaxf(fmaf(v.x, sc0, sh0), 0.f);
    a1 += fmaxf(fmaf(v.y, sc1, sh1), 0.f);
    c += 1.0f;
  }
  atomicAdd(&pool[curg * DIM + f0], a0);
  atomicAdd(&pool[curg * DIM + f1], a1);
  if (lane == 0) atomicAdd(&pcnt[curg], c);
}

// ---------------------------------------------------------------- output head
__global__ __launch_bounds__(256) void out_kernel(
    const float* __restrict__ pool, const float* __restrict__ pcnt,
    const float* __restrict__ Wout, const float* __restrict__ bout,
    float* __restrict__ out) {
  int idx = blockIdx.x * blockDim.x + threadIdx.x;
  if (idx >= NGRAPH * NTASK) return;
  int g = idx / NTASK, tt = idx % NTASK;
  float inv = 1.0f / fmaxf(pcnt[g], 1.0f);
  float acc = bout[tt];
  for (int d = 0; d < DIM; d++)
    acc = fmaf(pool[g * DIM + d] * inv, Wout[d * NTASK + tt], acc);
  out[idx] = acc;
}

// ----------------------------------------------------------------
extern "C" void kernel_launch(void* const* d_in, const int* in_sizes, int n_in,
                              void* d_out, int out_size, void* d_ws, size_t ws_size,
                              hipStream_t stream) {
  const float* x     = (const float*)d_in[0];
  const int*   eidx  = (const int*)d_in[1];
  const int*   row   = eidx;
  const int*   col   = eidx + N_EDGES;
  const int*   eattr = (const int*)d_in[2];
  const int*   batch = (const int*)d_in[3];
  const float* W     = (const float*)d_in[4];
  const float* b     = (const float*)d_in[5];
  const float* root  = (const float*)d_in[6];
  const float* bond  = (const float*)d_in[7];
  const float* gamma = (const float*)d_in[8];
  const float* beta  = (const float*)d_in[9];
  const float* Wout  = (const float*)d_in[10];
  const float* bout  = (const float*)d_in[11];
  float* out = (float*)d_out;

  // bump allocator over workspace (needs ~170 MB)
  char* w = (char*)d_ws;
  size_t off = 0;
  auto alloc = [&](size_t bytes) -> void* {
    void* p = w + off;
    off = (off + bytes + 511) & ~(size_t)511;
    return p;
  };
  // zero-init region (single memset): histograms, scatter positions, pool accumulators
  int*   cnt_row = (int*)alloc(N_NODES * 4);
  int*   cnt_col = (int*)alloc(N_NODES * 4);
  int*   pos     = (int*)alloc(N_NODES * 4);
  float* pool    = (float*)alloc(NGRAPH * DIM * 4);
  float* pcnt    = (float*)alloc(NGRAPH * 4);
  size_t zbytes  = off;
  // rest
  int*   csr     = (int*)alloc((N_NODES + 1) * 4);
  int*   bsum    = (int*)alloc(512 * 4);
  int*   bexcl   = (int*)alloc(512 * 4);
  float* deg     = (float*)alloc(N_NODES * 4);
  float* dinv    = (float*)alloc(N_NODES * 4);
  int*   spck    = (int*)alloc((size_t)N_EDGES * 4);
  float* enorm   = (float*)alloc((size_t)N_EDGES * 4);
  float* hx      = (float*)alloc((size_t)N_NODES * DIM * 4);
  float* hA      = (float*)alloc((size_t)N_NODES * DIM * 4);
  float* hB      = (float*)alloc((size_t)N_NODES * DIM * 4);
  float* bnbuf   = (float*)alloc(256 * 4);
  float* bnscale = (float*)alloc(DIM * 4);
  float* bnshift = (float*)alloc(DIM * 4);

  hipMemsetAsync(d_ws, 0, zbytes, stream);

  hist_kernel<<<2048, 256, 0, stream>>>(row, col, cnt_row, cnt_col);
  deg_kernel<<<(N_NODES + 255) / 256, 256, 0, stream>>>(cnt_row, deg, dinv);
  const int nb = (N_NODES + 255) / 256;  // 391
  scan1_kernel<<<nb, 256, 0, stream>>>(cnt_col, csr, bsum);
  scan2_kernel<<<1, 512, 0, stream>>>(bsum, bexcl, nb);
  scan3_kernel<<<nb, 256, 0, stream>>>(csr, bexcl);
  scatter_kernel<<<2048, 256, 0, stream>>>(row, col, eattr, csr, pos, dinv, spck, enorm);

  const float* hin = x;
  for (int l = 0; l < NLAYER; l++) {
    float* h2 = (l % 2 == 0) ? hA : hB;
    gemm_kernel<<<2048, 128, 0, stream>>>(
        hin, W + (size_t)l * DIM * DIM, b + l * DIM,
        bnscale, bnshift, (l > 0) ? 1 : 0, hx, bnbuf);
    agg_kernel<<<2048, 256, 0, stream>>>(
        hx, csr, spck, enorm, bond + (size_t)l * NBOND * DIM, root + l * DIM,
        deg, h2, bnbuf);
    bnfin_kernel<<<1, 128, 0, stream>>>(bnbuf, gamma + l * DIM, beta + l * DIM,
                                        bnscale, bnshift);
    hin = h2;
  }
  pool_kernel<<<256, 256, 0, stream>>>(hin, batch, bnscale, bnshift, pool, pcnt);
  out_kernel<<<5, 256, 0, stream>>>(pool, bnscale ? pcnt : pcnt, Wout, bout, out);
}